// Round 8
// baseline (1885.682 us; speedup 1.0000x reference)
//
#include <hip/hip_runtime.h>
#include <math.h>

#define MSZ   1048576ull  // 1024*1024 elements per matrix slot
#define NMAT  33          // matrix 0 = L0, matrices 1..32 = per-batch L
#define PANSZ 61440       // 960*64 shorts per matrix per panel plane
#define NSINK 14

__device__ __forceinline__ float frcp(float x){ return __builtin_amdgcn_rcpf(x); }

typedef __attribute__((ext_vector_type(8)))  short  bfrag;   // 8 x bf16 (4 VGPR)
typedef __attribute__((ext_vector_type(8)))  unsigned short u16x8;
typedef __attribute__((ext_vector_type(16))) float  f32x16;  // 32x32 acc

__device__ __forceinline__ unsigned short bf16rn(float x){
  unsigned u = __float_as_uint(x);
  unsigned r = u + 0x7fffu + ((u>>16)&1u);
  return (unsigned short)(r>>16);
}
__device__ __forceinline__ float bf2f(unsigned short h){
  return __uint_as_float(((unsigned)h)<<16);
}

// ---------------------------------------------------------------- setup
__global__ void k_misc(const float* __restrict__ Vc, float* __restrict__ V,
                       const float* __restrict__ W, float* __restrict__ Ws){
  int t = threadIdx.x;
  if(blockIdx.x < 4){
    int i = blockIdx.x*256 + t;
    float4 v = ((const float4*)Vc)[i];
    float mx = fmaxf(fmaxf(v.x,v.y), fmaxf(v.z,v.w));
    float e0=__expf(v.x-mx), e1=__expf(v.y-mx), e2=__expf(v.z-mx), e3=__expf(v.w-mx);
    float is = 1.f/(e0+e1+e2+e3);
    ((float4*)V)[i] = make_float4(e0*is, e1*is, e2*is, e3*is);
  } else {
    int idx = (blockIdx.x-4)*256 + t;
    int i = idx>>10, j = idx&1023;
    float v = 0.f;
    if(i != j){
      float w = (i>j) ? W[i*1024+j] : W[j*1024+i];
      v = 1.f/(1.f+__expf(-w));
    }
    Ws[idx]=v;
  }
}

// y[b] = sum_i log(V[i,x[b,i]] + 1e-7)
__global__ void k_pr_y(const float* __restrict__ V, const int* __restrict__ x,
                       float* __restrict__ y){
  int b = blockIdx.x, t = threadIdx.x;
  __shared__ float red[256];
  float acc = 0.f;
  for(int i=t; i<1024; i+=256){
    int xv = x[b*1024+i];
    acc += logf(V[i*4+xv] + 1e-7f);
  }
  red[t]=acc; __syncthreads();
  for(int s=128;s>0;s>>=1){ if(t<s) red[t]+=red[t+s]; __syncthreads(); }
  if(t==0) y[b]=red[0];
}

// ---------------------------------------------------------------- sinkhorn + WP
// PrInv folded into the LDS table: sE'[q] = clip(E)*ws*1/(av[qr]*bv[qc]).
__global__ void __launch_bounds__(256) k_sinkhorn(
    const float* __restrict__ Ec, const float* __restrict__ V,
    const float* __restrict__ Ws, const int* __restrict__ x,
    float* __restrict__ mats, float* __restrict__ partial){
  int idx = blockIdx.x*256 + threadIdx.x;
  int i = idx>>10, j = idx&1023;   // block covers fixed i, 256 consecutive j
  if(i==0) return;                 // row 0 of WP never needed (whole blocks)
  int t = threadIdx.x;
  int lane = t & 63, wv = t >> 6;
  __shared__ float sE[256][17];
  float E[16];
  {
    const float4* p = (const float4*)(Ec + (size_t)idx*16);
    float4 q0=p[0], q1=p[1], q2=p[2], q3=p[3];
    E[0]=__expf(q0.x); E[1]=__expf(q0.y); E[2]=__expf(q0.z); E[3]=__expf(q0.w);
    E[4]=__expf(q1.x); E[5]=__expf(q1.y); E[6]=__expf(q1.z); E[7]=__expf(q1.w);
    E[8]=__expf(q2.x); E[9]=__expf(q2.y); E[10]=__expf(q2.z); E[11]=__expf(q2.w);
    E[12]=__expf(q3.x);E[13]=__expf(q3.y);E[14]=__expf(q3.z); E[15]=__expf(q3.w);
  }
  float s0=0.f;
  #pragma unroll
  for(int q=0;q<16;q++) s0+=E[q];
  float is0 = frcp(s0);
  #pragma unroll
  for(int q=0;q<16;q++) E[q]*=is0;
  float av[4], bv[4];
  {
    float4 va = ((const float4*)V)[i];
    av[0]=va.x; av[1]=va.y; av[2]=va.z; av[3]=va.w;
    float4 vb = ((const float4*)V)[j];
    bv[0]=vb.x; bv[1]=vb.y; bv[2]=vb.z; bv[3]=vb.w;
  }
  for(int it=0; it<NSINK; ++it){
    #pragma unroll
    for(int r=0;r<4;r++){
      float rs = E[4*r]+E[4*r+1]+E[4*r+2]+E[4*r+3];
      float sc = av[r]*frcp(rs+1e-7f);
      E[4*r]*=sc; E[4*r+1]*=sc; E[4*r+2]*=sc; E[4*r+3]*=sc;
    }
    #pragma unroll
    for(int c=0;c<4;c++){
      float cs = E[c]+E[4+c]+E[8+c]+E[12+c];
      float sc = bv[c]*frcp(cs+1e-7f);
      E[c]*=sc; E[4+c]*=sc; E[8+c]*=sc; E[12+c]*=sc;
    }
  }
  float wsij = Ws[idx];                 // 0 on diagonal -> val=0 there
  #pragma unroll
  for(int q=0;q<16;q++){
    float e = fminf(fmaxf(E[q],0.f),1.f);
    sE[t][q] = e * wsij * frcp(av[q>>2]*bv[q&3]);
  }
  for(int b=0;b<32;b++){
    int xi = x[b*1024+i];               // uniform per block -> scalar load
    int xj = x[b*1024+j];
    float val = sE[t][(xi<<2)+xj];
    if(j!=0)                            // j==0 exists only in the row sum
      mats[(size_t)(1+b)*MSZ + (size_t)(i-1)*1024 + (j-1)] = 1e-7f - val;
    float r = val;                      // wave-reduce row-sum contribution
    r += __shfl_down(r,32); r += __shfl_down(r,16); r += __shfl_down(r,8);
    r += __shfl_down(r,4);  r += __shfl_down(r,2);  r += __shfl_down(r,1);
    if(lane==0)
      partial[((size_t)b<<14) + ((size_t)(i-1)<<4) + ((blockIdx.x&3)<<2) + wv] = r;
  }
}

// ---------------------------------------------------------------- L0 build
__global__ void k_l0(const float* __restrict__ Ws, float* __restrict__ mats){
  int r = blockIdx.x, t = threadIdx.x;
  float* orow = mats + (size_t)r*1024;
  if(r == 1023){
    float4 o = make_float4(0.f,0.f,0.f,0.f);
    if(t==255) o.w = 1.f;
    ((float4*)orow)[t] = o;
    return;
  }
  const float* wrow = Ws + (size_t)(r+1)*1024;
  float4 v = ((const float4*)wrow)[t];
  __shared__ float red[256];
  red[t] = v.x+v.y+v.z+v.w;
  __syncthreads();
  for(int s=128;s>0;s>>=1){ if(t<s) red[t]+=red[t+s]; __syncthreads(); }
  float rs = red[0];
  float o[4];
  #pragma unroll
  for(int q=0;q<4;q++){
    int c = 4*t+q;
    if(c==r)          o[q] = rs + 1e-7f;
    else if(c < 1023) o[q] = 1e-7f - wrow[c+1];
    else              o[q] = 0.f;
  }
  ((float4*)orow)[t] = make_float4(o[0],o[1],o[2],o[3]);
}

// Patch batch matrices: diagonal = rowsum+1e-7 (from partials), clear padding.
__global__ void k_patch(float* __restrict__ mats, const float* __restrict__ partial){
  int m = blockIdx.y + 1;
  int r = blockIdx.x*256 + threadIdx.x;   // 0..1023
  float* A = mats + (size_t)m*MSZ;
  A[(size_t)r*1024 + 1023] = (r==1023) ? 1.f : 0.f;
  if(r < 1023){
    A[(size_t)1023*1024 + r] = 0.f;
    const float* pp = partial + (((size_t)(m-1))<<14) + ((size_t)r<<4);
    float s = 0.f;
    #pragma unroll
    for(int q=0;q<16;q++) s += pp[q];
    A[(size_t)r*1024 + r] = s + 1e-7f;
  }
}

// ---------------------------------------------------------------- LU panel
// (unchanged from R7 — verified) Wave 0 of every block computes the 64x64
// diagonal LU into LDS; block (0,m) updates logdet.  256 threads then do the
// L21/U12 solves via LDS broadcast.  Outputs pre-split bf16 hi/lo panels.
__global__ void __launch_bounds__(256) k_panel(float* __restrict__ mats,
    unsigned short* __restrict__ Ah, unsigned short* __restrict__ Al,
    unsigned short* __restrict__ Bh, unsigned short* __restrict__ Bl,
    float* __restrict__ logdet, int k){
  int m = blockIdx.y;
  float* A = mats + (size_t)m*MSZ;
  int rem = 1024 - (k+64);
  int nb = (rem + 255) >> 8;
  int t = threadIdx.x;
  int lane = t & 63, wvi = t >> 6;
  __shared__ float Ld[4096];
  __shared__ float Ud[4096];

  if(wvi==0){
    float row[64];
    #pragma unroll
    for(int q=0;q<64;q++)
      row[q] = A[(size_t)(k+lane)*1024 + k + q];
    float slog = 0.f;
    #pragma unroll
    for(int c=0;c<64;c++){
      float piv = __shfl(row[c], c);
      slog += logf(fabsf(piv));
      float ip = frcp(piv);
      bool below = lane > c;
      float lic = below ? row[c]*ip : 0.f;
      row[c] = below ? lic : row[c];
      if(below) Ld[lane*64 + c] = lic;
      #pragma unroll
      for(int q=c+1;q<64;q++){
        float uq = __shfl(row[q], c);
        row[q] = fmaf(-lic, uq, row[q]);
      }
    }
    #pragma unroll
    for(int q=0;q<64;q++)
      if(q>=lane) Ud[lane*64 + q] = row[q];
    if(lane==0 && blockIdx.x==0){
      if(k==0) logdet[m] = slog; else logdet[m] += slog;
    }
  }
  __syncthreads();

  float v[64];
  unsigned short* Ph; unsigned short* Pl; int rel; bool act;
  if((int)blockIdx.x < nb){
    rel = blockIdx.x*256 + t;
    act = rel < rem;
    int i = k + 64 + rel;
    size_t base = (size_t)i*1024 + k;
    const float4* pb = (const float4*)(A + (act ? base : 0));
    #pragma unroll
    for(int q4=0;q4<16;q4++){
      float4 w = act ? pb[q4] : make_float4(0.f,0.f,0.f,0.f);
      v[4*q4]=w.x; v[4*q4+1]=w.y; v[4*q4+2]=w.z; v[4*q4+3]=w.w;
    }
    #pragma unroll
    for(int p=0;p<64;p++){
      float xp = v[p]*frcp(Ud[p*64+p]);
      v[p] = xp;
      #pragma unroll
      for(int q=p+1;q<64;q++) v[q] = fmaf(-xp, Ud[p*64+q], v[q]);
    }
    Ph = Ah + (size_t)m*PANSZ; Pl = Al + (size_t)m*PANSZ;
  } else {
    rel = (blockIdx.x - nb)*256 + t;
    act = rel < rem;
    int col = k + 64 + rel;
    #pragma unroll
    for(int r=0;r<64;r++) v[r] = act ? A[(size_t)(k+r)*1024 + col] : 0.f;
    #pragma unroll
    for(int r=1;r<64;r++){
      float s = v[r];
      #pragma unroll
      for(int p=0;p<r;p++) s = fmaf(-Ld[r*64+p], v[p], s);
      v[r] = s;
    }
    Ph = Bh + (size_t)m*PANSZ; Pl = Bl + (size_t)m*PANSZ;
  }
  if(act){
    u16x8* ph = (u16x8*)(Ph + (size_t)rel*64);
    u16x8* pl = (u16x8*)(Pl + (size_t)rel*64);
    #pragma unroll
    for(int q8=0;q8<8;q8++){
      u16x8 h8, l8;
      #pragma unroll
      for(int e=0;e<8;e++){
        float xv = v[q8*8+e];
        unsigned short h = bf16rn(xv);
        h8[e] = h;
        l8[e] = bf16rn(xv - bf2f(h));
      }
      ph[q8] = h8;
      pl[q8] = l8;
    }
  }
}

// ------------------------------------------------- strip update (rank-64 RMW)
// After panel(k): update ONLY the next 64-wide strip at k2=k+64 so panel(k2)
// can run; trailing >= k+128 is deferred to k_gemm128.  MFMA frags are read
// DIRECTLY from the global bf16 panels (layout matches frag layout; L2-hot).
//  col strip: rows k2..1024 (rem2+64 rows, last tile 64-row overhang), cols k2..k2+64
//  row strip: rows k2..k2+64, cols k2+64..1024 (rem2 cols, exact tiles)
__global__ void __launch_bounds__(256) k_sgemm(float* __restrict__ mats,
    const unsigned short* __restrict__ Ah, const unsigned short* __restrict__ Al,
    const unsigned short* __restrict__ Bh, const unsigned short* __restrict__ Bl,
    int k){
  int m = blockIdx.y;
  float* A = mats + (size_t)m*MSZ;
  int k2 = k + 64;
  int rem2 = 1024 - (k2+64);            // multiple of 128
  int nct = (rem2 + 64 + 127) >> 7;     // col-strip tiles of 128 rows
  int t = threadIdx.x;
  int lane = t & 63, wvi = t >> 6;
  int kgrp = lane >> 5;
  const unsigned short* pAh = Ah + (size_t)m*PANSZ;
  const unsigned short* pAl = Al + (size_t)m*PANSZ;
  const unsigned short* pBh = Bh + (size_t)m*PANSZ;
  const unsigned short* pBl = Bl + (size_t)m*PANSZ;

  f32x16 acc[2];
  #pragma unroll
  for(int u=0;u<2;u++)
    #pragma unroll
    for(int q=0;q<16;q++) acc[u][q] = 0.f;

  if((int)blockIdx.x < nct){
    // ---- column strip: C rows = strip rows rbase.., C cols = 0..63 (rel k2)
    int rbase = blockIdx.x*128 + wvi*32;
    int maxrow = rem2 + 63;             // last valid strip row index
    int arow = rbase + (lane&31);
    int arowc = (arow > maxrow) ? maxrow : arow;   // clamp loads; stores guarded
    #pragma unroll
    for(int kc=0;kc<4;kc++){
      int koct = kc*2 + kgrp;
      bfrag ah = *(const bfrag*)(pAh + (size_t)arowc*64 + koct*8);
      bfrag al = *(const bfrag*)(pAl + (size_t)arowc*64 + koct*8);
      #pragma unroll
      for(int ct=0;ct<2;ct++){
        int bcol = ct*32 + (lane&31);
        bfrag bh = *(const bfrag*)(pBh + (size_t)bcol*64 + koct*8);
        bfrag bl = *(const bfrag*)(pBl + (size_t)bcol*64 + koct*8);
        acc[ct] = __builtin_amdgcn_mfma_f32_32x32x16_bf16(ah, bh, acc[ct], 0,0,0);
        acc[ct] = __builtin_amdgcn_mfma_f32_32x32x16_bf16(ah, bl, acc[ct], 0,0,0);
        acc[ct] = __builtin_amdgcn_mfma_f32_32x32x16_bf16(al, bh, acc[ct], 0,0,0);
      }
    }
    #pragma unroll
    for(int ct=0;ct<2;ct++){
      int gc = k2 + ct*32 + (lane&31);
      #pragma unroll
      for(int reg=0;reg<16;reg++){
        int sr = rbase + ((lane>>5)<<2) + (reg&3) + ((reg>>2)<<3);
        if(sr <= maxrow){
          float* pc = A + (size_t)(k2+sr)*1024 + gc;
          *pc -= acc[ct][reg];
        }
      }
    }
  } else {
    // ---- row strip: C rows = 0..63 (rel k2), C cols = k2+64+cbase..
    int cbase = (blockIdx.x - nct)*128 + wvi*32;
    int bcol = 64 + cbase + (lane&31);  // panel B index
    #pragma unroll
    for(int kc=0;kc<4;kc++){
      int koct = kc*2 + kgrp;
      bfrag bh = *(const bfrag*)(pBh + (size_t)bcol*64 + koct*8);
      bfrag bl = *(const bfrag*)(pBl + (size_t)bcol*64 + koct*8);
      #pragma unroll
      for(int rt=0;rt<2;rt++){
        int arow = rt*32 + (lane&31);
        bfrag ah = *(const bfrag*)(pAh + (size_t)arow*64 + koct*8);
        bfrag al = *(const bfrag*)(pAl + (size_t)arow*64 + koct*8);
        acc[rt] = __builtin_amdgcn_mfma_f32_32x32x16_bf16(ah, bh, acc[rt], 0,0,0);
        acc[rt] = __builtin_amdgcn_mfma_f32_32x32x16_bf16(ah, bl, acc[rt], 0,0,0);
        acc[rt] = __builtin_amdgcn_mfma_f32_32x32x16_bf16(al, bh, acc[rt], 0,0,0);
      }
    }
    int gc = k2 + 64 + cbase + (lane&31);
    #pragma unroll
    for(int rt=0;rt<2;rt++){
      #pragma unroll
      for(int reg=0;reg<16;reg++){
        int gr = k2 + rt*32 + ((lane>>5)<<2) + (reg&3) + ((reg>>2)<<3);
        float* pc = A + (size_t)gr*1024 + gc;
        *pc -= acc[rt][reg];
      }
    }
  }
}

// ------------------------------------------------- rank-128 trailing update
// A22 -= [L1|L2]·[U1;U2] for trailing >= k+128.  4 K=32 LDS stages: stages
// 0/1 from P1 panels (row idx rel+64), stages 2/3 from P2 (row idx rel).
// C RMW once.  32 KB LDS, prefetch next stage before each barrier.
__global__ void __launch_bounds__(256) k_gemm128(float* __restrict__ mats,
    const unsigned short* __restrict__ A1h, const unsigned short* __restrict__ A1l,
    const unsigned short* __restrict__ B1h, const unsigned short* __restrict__ B1l,
    const unsigned short* __restrict__ A2h, const unsigned short* __restrict__ A2l,
    const unsigned short* __restrict__ B2h, const unsigned short* __restrict__ B2l,
    int k){
  int m = blockIdx.z;
  float* A = mats + (size_t)m*MSZ;
  int rem = 1024 - (k+128);
  int i0rel = blockIdx.y*128;
  int j0rel = blockIdx.x*128;
  __shared__ unsigned short As[2][4096];
  __shared__ unsigned short Bs[2][4096];
  int t = threadIdx.x;
  int lane = t & 63, wvi = t >> 6;
  int wr = wvi >> 1, wc = wvi & 1;

  const unsigned short* srcAh[2] = {A1h + (size_t)m*PANSZ, A2h + (size_t)m*PANSZ};
  const unsigned short* srcAl[2] = {A1l + (size_t)m*PANSZ, A2l + (size_t)m*PANSZ};
  const unsigned short* srcBh[2] = {B1h + (size_t)m*PANSZ, B2h + (size_t)m*PANSZ};
  const unsigned short* srcBl[2] = {B1l + (size_t)m*PANSZ, B2l + (size_t)m*PANSZ};

  int ldsOff[2]; bool vA[2], vB[2];
  size_t rA[2][2], rB[2][2];   // [panelset][pos] row-base offsets
  int koA[2];
  #pragma unroll
  for(int p=0;p<2;p++){
    int c = t + 256*p;
    int row = c>>2, koct = c&3;
    koA[p] = koct*8;
    ldsOff[p] = row*32 + ((koct ^ ((row>>1)&3))<<3);
    vA[p] = (i0rel+row) < rem;
    vB[p] = (j0rel+row) < rem;
    rA[0][p] = (size_t)(i0rel+row+64)*64;   // P1
    rB[0][p] = (size_t)(j0rel+row+64)*64;
    rA[1][p] = (size_t)(i0rel+row)*64;      // P2
    rB[1][p] = (size_t)(j0rel+row)*64;
  }
  u16x8 z; z = 0;
  u16x8 cur[8], nxt[8];
  // load stage 0 (P1, koff 0)
  #pragma unroll
  for(int p=0;p<2;p++){
    cur[4*p+0] = vA[p] ? *(const u16x8*)(srcAh[0] + rA[0][p] + koA[p]) : z;
    cur[4*p+1] = vA[p] ? *(const u16x8*)(srcAl[0] + rA[0][p] + koA[p]) : z;
    cur[4*p+2] = vB[p] ? *(const u16x8*)(srcBh[0] + rB[0][p] + koA[p]) : z;
    cur[4*p+3] = vB[p] ? *(const u16x8*)(srcBl[0] + rB[0][p] + koA[p]) : z;
  }

  f32x16 acc[2][2];
  #pragma unroll
  for(int rt=0;rt<2;rt++)
    #pragma unroll
    for(int ct=0;ct<2;ct++)
      #pragma unroll
      for(int q=0;q<16;q++) acc[rt][ct][q] = 0.f;

  int kgrp = lane >> 5;
  #pragma unroll
  for(int st=0; st<4; st++){
    if(st) __syncthreads();
    #pragma unroll
    for(int p=0;p<2;p++){
      *(u16x8*)&As[0][ldsOff[p]] = cur[4*p+0];
      *(u16x8*)&As[1][ldsOff[p]] = cur[4*p+1];
      *(u16x8*)&Bs[0][ldsOff[p]] = cur[4*p+2];
      *(u16x8*)&Bs[1][ldsOff[p]] = cur[4*p+3];
    }
    if(st<3){
      int ns = st+1;
      int set = ns>>1, koff = (ns&1)*32;
      #pragma unroll
      for(int p=0;p<2;p++){
        nxt[4*p+0] = vA[p] ? *(const u16x8*)(srcAh[set] + rA[set][p] + koff + koA[p]) : z;
        nxt[4*p+1] = vA[p] ? *(const u16x8*)(srcAl[set] + rA[set][p] + koff + koA[p]) : z;
        nxt[4*p+2] = vB[p] ? *(const u16x8*)(srcBh[set] + rB[set][p] + koff + koA[p]) : z;
        nxt[4*p+3] = vB[p] ? *(const u16x8*)(srcBl[set] + rB[set][p] + koff + koA[p]) : z;
      }
    }
    __syncthreads();
    #pragma unroll
    for(int kc=0;kc<2;kc++){
      int koct = kc*2 + kgrp;
      bfrag ah[2], al[2], bh[2], bl[2];
      #pragma unroll
      for(int rt=0;rt<2;rt++){
        int row = wr*64 + rt*32 + (lane&31);
        int ad = row*32 + ((koct ^ ((row>>1)&3))<<3);
        ah[rt] = *(const bfrag*)&As[0][ad];
        al[rt] = *(const bfrag*)&As[1][ad];
      }
      #pragma unroll
      for(int ct=0;ct<2;ct++){
        int col = wc*64 + ct*32 + (lane&31);
        int ad = col*32 + ((koct ^ ((col>>1)&3))<<3);
        bh[ct] = *(const bfrag*)&Bs[0][ad];
        bl[ct] = *(const bfrag*)&Bs[1][ad];
      }
      #pragma unroll
      for(int rt=0;rt<2;rt++)
        #pragma unroll
        for(int ct=0;ct<2;ct++){
          acc[rt][ct] = __builtin_amdgcn_mfma_f32_32x32x16_bf16(ah[rt], bh[ct], acc[rt][ct], 0,0,0);
          acc[rt][ct] = __builtin_amdgcn_mfma_f32_32x32x16_bf16(ah[rt], bl[ct], acc[rt][ct], 0,0,0);
          acc[rt][ct] = __builtin_amdgcn_mfma_f32_32x32x16_bf16(al[rt], bh[ct], acc[rt][ct], 0,0,0);
        }
    }
    if(st<3){
      #pragma unroll
      for(int q=0;q<8;q++) cur[q] = nxt[q];
    }
  }

  // C RMW epilogue, once
  int r0 = k + 128;
  #pragma unroll
  for(int rt=0;rt<2;rt++){
    int rowblk = i0rel + wr*64 + rt*32;
    if(rowblk >= rem) continue;
    #pragma unroll
    for(int ct=0;ct<2;ct++){
      int colblk = j0rel + wc*64 + ct*32;
      if(colblk >= rem) continue;
      int col = r0 + colblk + (lane&31);
      int rbase = r0 + rowblk + ((lane>>5)<<2);
      #pragma unroll
      for(int reg=0;reg<16;reg++){
        int row = rbase + (reg&3) + ((reg>>2)<<3);
        float* pc = A + (size_t)row*1024 + col;
        *pc -= acc[rt][ct][reg];
      }
    }
  }
}

// ------------------------------------------------- rank-64 trailing (final step)
__global__ void __launch_bounds__(256) k_gemm(float* __restrict__ mats,
    const unsigned short* __restrict__ Ah, const unsigned short* __restrict__ Al,
    const unsigned short* __restrict__ Bh, const unsigned short* __restrict__ Bl,
    int k){
  int m = blockIdx.z;
  float* A = mats + (size_t)m*MSZ;
  int rem = 1024 - (k+64);
  int i0rel = blockIdx.y*128;
  int j0rel = blockIdx.x*128;
  __shared__ unsigned short As[2][4096];
  __shared__ unsigned short Bs[2][4096];
  int t = threadIdx.x;
  int lane = t & 63, wvi = t >> 6;
  int wr = wvi >> 1, wc = wvi & 1;

  const unsigned short* pAh = Ah + (size_t)m*PANSZ;
  const unsigned short* pAl = Al + (size_t)m*PANSZ;
  const unsigned short* pBh = Bh + (size_t)m*PANSZ;
  const unsigned short* pBl = Bl + (size_t)m*PANSZ;

  int ldsOff[2];
  bool vA[2], vB[2];
  size_t offA[2], offB[2];
  #pragma unroll
  for(int p=0;p<2;p++){
    int c = t + 256*p;
    int row = c>>2, koct = c&3;
    ldsOff[p] = row*32 + ((koct ^ ((row>>1)&3))<<3);
    vA[p] = (i0rel+row) < rem;
    vB[p] = (j0rel+row) < rem;
    offA[p] = (size_t)(i0rel+row)*64 + koct*8;
    offB[p] = (size_t)(j0rel+row)*64 + koct*8;
  }
  u16x8 z; z = 0;
  #pragma unroll
  for(int p=0;p<2;p++){
    u16x8 ah = vA[p] ? *(const u16x8*)(pAh + offA[p]) : z;
    u16x8 al = vA[p] ? *(const u16x8*)(pAl + offA[p]) : z;
    u16x8 bh = vB[p] ? *(const u16x8*)(pBh + offB[p]) : z;
    u16x8 bl = vB[p] ? *(const u16x8*)(pBl + offB[p]) : z;
    *(u16x8*)&As[0][ldsOff[p]] = ah;
    *(u16x8*)&As[1][ldsOff[p]] = al;
    *(u16x8*)&Bs[0][ldsOff[p]] = bh;
    *(u16x8*)&Bs[1][ldsOff[p]] = bl;
  }
  u16x8 p1[8];
  #pragma unroll
  for(int p=0;p<2;p++){
    p1[4*p+0] = vA[p] ? *(const u16x8*)(pAh + offA[p] + 32) : z;
    p1[4*p+1] = vA[p] ? *(const u16x8*)(pAl + offA[p] + 32) : z;
    p1[4*p+2] = vB[p] ? *(const u16x8*)(pBh + offB[p] + 32) : z;
    p1[4*p+3] = vB[p] ? *(const u16x8*)(pBl + offB[p] + 32) : z;
  }
  __syncthreads();

  f32x16 acc[2][2];
  #pragma unroll
  for(int rt=0;rt<2;rt++)
    #pragma unroll
    for(int ct=0;ct<2;ct++)
      #pragma unroll
      for(int q=0;q<16;q++) acc[rt][ct][q] = 0.f;

  int kgrp = lane >> 5;
  #pragma unroll
  for(int ks=0; ks<2; ks++){
    #pragma unroll
    for(int kc=0;kc<2;kc++){
      int koct = kc*2 + kgrp;
      bfrag ah[2], al[2], bh[2], bl[2];
      #pragma unroll
      for(int rt=0;rt<2;rt++){
        int row = wr*64 + rt*32 + (lane&31);
        int ad = row*32 + ((koct ^ ((row>>1)&3))<<3);
        ah[rt] = *(const bfrag*)&As[0][ad];
        al[rt] = *(const bfrag*)&As[1][ad];
      }
      #pragma unroll
      for(int ct=0;ct<2;ct++){
        int col = wc*64 + ct*32 + (lane&31);
        int ad = col*32 + ((koct ^ ((col>>1)&3))<<3);
        bh[ct] = *(const bfrag*)&Bs[0][ad];
        bl[ct] = *(const bfrag*)&Bs[1][ad];
      }
      #pragma unroll
      for(int rt=0;rt<2;rt++)
        #pragma unroll
        for(int ct=0;ct<2;ct++){
          acc[rt][ct] = __builtin_amdgcn_mfma_f32_32x32x16_bf16(ah[rt], bh[ct], acc[rt][ct], 0,0,0);
          acc[rt][ct] = __builtin_amdgcn_mfma_f32_32x32x16_bf16(ah[rt], bl[ct], acc[rt][ct], 0,0,0);
          acc[rt][ct] = __builtin_amdgcn_mfma_f32_32x32x16_bf16(al[rt], bh[ct], acc[rt][ct], 0,0,0);
        }
    }
    if(ks==0){
      __syncthreads();
      #pragma unroll
      for(int p=0;p<2;p++){
        *(u16x8*)&As[0][ldsOff[p]] = p1[4*p+0];
        *(u16x8*)&As[1][ldsOff[p]] = p1[4*p+1];
        *(u16x8*)&Bs[0][ldsOff[p]] = p1[4*p+2];
        *(u16x8*)&Bs[1][ldsOff[p]] = p1[4*p+3];
      }
      __syncthreads();
    }
  }

  int r0 = k + 64;
  #pragma unroll
  for(int rt=0;rt<2;rt++){
    int rowblk = i0rel + wr*64 + rt*32;
    if(rowblk >= rem) continue;
    #pragma unroll
    for(int ct=0;ct<2;ct++){
      int colblk = j0rel + wc*64 + ct*32;
      if(colblk >= rem) continue;
      int col = r0 + colblk + (lane&31);
      int rbase = r0 + rowblk + ((lane>>5)<<2);
      #pragma unroll
      for(int reg=0;reg<16;reg++){
        int row = rbase + (reg&3) + ((reg>>2)<<3);
        float* pc = A + (size_t)row*1024 + col;
        *pc -= acc[rt][ct][reg];
      }
    }
  }
}

// Final 64x64 block (k=960): logdet contribution only.
__global__ void __launch_bounds__(64) k_ld(const float* __restrict__ mats,
                                           float* __restrict__ logdet){
  int m = blockIdx.x, t = threadIdx.x;
  const float* A = mats + (size_t)m*MSZ;
  float row[64];
  #pragma unroll
  for(int q=0;q<64;q++)
    row[q] = A[(size_t)(960+t)*1024 + 960 + q];
  float slog = 0.f;
  #pragma unroll
  for(int c=0;c<64;c++){
    float piv = __shfl(row[c], c);
    slog += logf(fabsf(piv));
    float ip = frcp(piv);
    bool below = t > c;
    float lic = below ? row[c]*ip : 0.f;
    #pragma unroll
    for(int q=c+1;q<64;q++){
      float uq = __shfl(row[q], c);
      row[q] = fmaf(-lic, uq, row[q]);
    }
  }
  if(t==0) logdet[m] += slog;
}

__global__ void k_final(const float* __restrict__ y, const float* __restrict__ logdet,
                        float* __restrict__ out){
  int b = threadIdx.x;
  if(b<32) out[b] = y[b] + logdet[1+b] - logdet[0];
}

// ---------------------------------------------------------------- launch
extern "C" void kernel_launch(void* const* d_in, const int* in_sizes, int n_in,
                              void* d_out, int out_size, void* d_ws, size_t ws_size,
                              hipStream_t stream){
  (void)in_sizes; (void)n_in; (void)out_size; (void)ws_size;
  const int*   x  = (const int*)d_in[0];
  const float* W  = (const float*)d_in[1];
  const float* Vc = (const float*)d_in[2];
  const float* Ec = (const float*)d_in[3];
  float* out = (float*)d_out;

  char* p = (char*)d_ws;
  auto alloc = [&](size_t bytes)->char*{ char* r = p; p += (bytes+255)&~(size_t)255; return r; };
  float* mats   = (float*)alloc((size_t)NMAT*MSZ*4);           // 138.4 MB
  float* Ws     = (float*)alloc(1048576ull*4);
  unsigned short* A1h = (unsigned short*)alloc((size_t)NMAT*PANSZ*2);
  unsigned short* A1l = (unsigned short*)alloc((size_t)NMAT*PANSZ*2);
  unsigned short* B1h = (unsigned short*)alloc((size_t)NMAT*PANSZ*2);
  unsigned short* B1l = (unsigned short*)alloc((size_t)NMAT*PANSZ*2);
  unsigned short* A2h = (unsigned short*)alloc((size_t)NMAT*PANSZ*2);
  unsigned short* A2l = (unsigned short*)alloc((size_t)NMAT*PANSZ*2);
  unsigned short* B2h = (unsigned short*)alloc((size_t)NMAT*PANSZ*2);
  unsigned short* B2l = (unsigned short*)alloc((size_t)NMAT*PANSZ*2);
  float* V      = (float*)alloc(4096*4);
  float* partial= (float*)alloc((size_t)32*16384*4);           // 2 MB
  float* y      = (float*)alloc(256);
  float* logdet = (float*)alloc(256);

  k_misc<<<4100,256,0,stream>>>(Vc, V, W, Ws);
  k_pr_y<<<32,256,0,stream>>>(V, x, y);
  k_sinkhorn<<<4096,256,0,stream>>>(Ec, V, Ws, x, mats, partial);
  k_l0<<<1024,256,0,stream>>>(Ws, mats);
  k_patch<<<dim3(4,32),256,0,stream>>>(mats, partial);

  for(int s=0;s<7;s++){
    int k = 128*s;
    // panel at k -> P1
    {
      int rem = 1024 - (k+64);
      int nbp = (rem+255)/256;
      k_panel<<<dim3(2*nbp,NMAT),256,0,stream>>>(mats, A1h, A1l, B1h, B1l, logdet, k);
    }
    // strip update at k+64 (rank-64, L-shaped region only)
    {
      int rem2 = 1024 - (k+128);
      int nct = (rem2 + 64 + 127) >> 7;
      int nrt = rem2 >> 7;
      k_sgemm<<<dim3(nct+nrt,NMAT),256,0,stream>>>(mats, A1h, A1l, B1h, B1l, k);
    }
    // panel at k+64 -> P2
    {
      int rem = 1024 - (k+128);
      int nbp = (rem+255)/256;
      k_panel<<<dim3(2*nbp,NMAT),256,0,stream>>>(mats, A2h, A2l, B2h, B2l, logdet, k+64);
    }
    // rank-128 trailing update
    {
      int rem = 1024 - (k+128);
      int nt = (rem+127)/128;
      k_gemm128<<<dim3(nt,nt,NMAT),256,0,stream>>>(mats, A1h,A1l,B1h,B1l,
                                                   A2h,A2l,B2h,B2l, k);
    }
  }
  // final 128: classic rank-64 step at k=896, then last diag logdet
  {
    int k = 896;
    int rem = 1024 - (k+64);            // 64
    int nbp = (rem+255)/256;            // 1
    k_panel<<<dim3(2*nbp,NMAT),256,0,stream>>>(mats, A1h, A1l, B1h, B1l, logdet, k);
    k_gemm<<<dim3(1,1,NMAT),256,0,stream>>>(mats, A1h, A1l, B1h, B1l, k);
  }
  k_ld<<<NMAT,64,0,stream>>>(mats, logdet);
  k_final<<<1,32,0,stream>>>(y, logdet, out);
}